// Round 8
// baseline (203.684 us; speedup 1.0000x reference)
//
#include <hip/hip_runtime.h>

// CoPE2d: B=64, NH=16, Wh=Ww=16, N=256, C=64, NPOS=288, BH=1024
// query (BH,256,64) f32; attn_logits (BH,256,256) f32; pos_emb (64,288) f32;
// out (BH,256,256) f32.
// One block = 4 consecutive 16-row blocks of one bh, software-pipelined with
// double-buffered bf16 L-table -> ONE barrier per step. 256 thr, 8 blocks/CU.

#define NPOS 288
#define NT   18          // npos tiles of 16
#define LTS2 292         // bf16 Ltab row stride (u16 elements)

typedef __attribute__((ext_vector_type(8))) short bf16x8;
typedef __attribute__((ext_vector_type(4))) float f32x4;

__device__ __forceinline__ unsigned short f2bf(float f) {   // RNE f32->bf16
    unsigned u = __float_as_uint(f);
    u += 0x7FFF + ((u >> 16) & 1);
    return (unsigned short)(u >> 16);
}
__device__ __forceinline__ float bf2f(unsigned short b) {
    return __uint_as_float(((unsigned)b) << 16);
}
// packed f32x2 -> bf16x2 (RNE), single VALU op
__device__ __forceinline__ unsigned cvt_pk_bf16(float lo, float hi) {
    unsigned r;
    asm("v_cvt_pk_bf16_f32 %0, %1, %2" : "=v"(r) : "v"(lo), "v"(hi));
    return r;
}

// dst[i] = src[i] + src[i+D] within 16-lane DPP rows, 0 beyond row end.
template <int D>
__device__ __forceinline__ float suffix_step(float v) {
    int s = __builtin_amdgcn_update_dpp(0, __float_as_int(v), 0x100 | D, 0xF, 0xF, true);
    return v + __int_as_float(s);
}

// ---- prep: pos_emb (64x288 f32) -> bf16 B-fragments in ws ------------------
__global__ void prep_kernel(const float* __restrict__ pos_emb,
                            short* __restrict__ wsb) {
    int idx = blockIdx.x * blockDim.x + threadIdx.x;   // 0 .. NT*2*64
    if (idx >= NT * 2 * 64) return;
    int l = idx & 63;
    int s = (idx >> 6) & 1;
    int t = idx >> 7;
    int col = t * 16 + (l & 15);
    int k0  = s * 32 + (l >> 4) * 8;
    short* dst = wsb + idx * 8;
    #pragma unroll
    for (int j = 0; j < 8; ++j)
        dst[j] = (short)f2bf(pos_emb[(k0 + j) * NPOS + col]);
}

__global__ __launch_bounds__(256, 8) void cope2d_kernel(
    const float* __restrict__ query,
    const float* __restrict__ attn_logits,
    const bf16x8* __restrict__ wsb8,
    float* __restrict__ out)
{
    __shared__ unsigned short Lb[2][16 * LTS2];   // 2 x 9344 B, double-buffered

    const int tid  = threadIdx.x;
    const int lane = tid & 63;
    const int wave = tid >> 6;
    const int blk  = blockIdx.x;               // 0..4095
    const int bh   = blk >> 2;
    const int p0   = (blk & 3) * 4;

    int rowbase = bh * 256 + p0 * 16;          // fits 32-bit
    int gb      = rowbase * 256;               // element idx < 2^26

    // ---- prologue: prefetch q + gates for step 0 ---------------------------
    const float* qp = query + rowbase * 64 + (lane & 15) * 64 + (lane >> 4) * 8;
    f32x4 q00 = *(const f32x4*)(qp);
    f32x4 q01 = *(const f32x4*)(qp + 4);
    f32x4 q10 = *(const f32x4*)(qp + 32);
    f32x4 q11 = *(const f32x4*)(qp + 36);
    float gn[16];
    {
        const float* gp = attn_logits + gb + tid;
        #pragma unroll
        for (int i = 0; i < 16; ++i)
            gn[i] = gp[i * 256];               // coalesced
    }

    for (int s = 0; s < 4; ++s) {
        // ---- A fragments via packed cvt (row=lane&15, k=(lane>>4)*8+j) -----
        union { bf16x8 v; unsigned u[4]; } A0, A1;
        A0.u[0] = cvt_pk_bf16(q00[0], q00[1]);
        A0.u[1] = cvt_pk_bf16(q00[2], q00[3]);
        A0.u[2] = cvt_pk_bf16(q01[0], q01[1]);
        A0.u[3] = cvt_pk_bf16(q01[2], q01[3]);
        A1.u[0] = cvt_pk_bf16(q10[0], q10[1]);
        A1.u[1] = cvt_pk_bf16(q10[2], q10[3]);
        A1.u[2] = cvt_pk_bf16(q11[0], q11[1]);
        A1.u[3] = cvt_pk_bf16(q11[2], q11[3]);

        // ---- MFMA GEMM -> Lb[s&1] (bf16) -----------------------------------
        unsigned short* Lbs = Lb[s & 1];
        for (int t = wave; t < NT; t += 4) {
            f32x4 c = {0.f, 0.f, 0.f, 0.f};
            c = __builtin_amdgcn_mfma_f32_16x16x32_bf16(A0.v, wsb8[(t * 2 + 0) * 64 + lane], c, 0, 0, 0);
            c = __builtin_amdgcn_mfma_f32_16x16x32_bf16(A1.v, wsb8[(t * 2 + 1) * 64 + lane], c, 0, 0, 0);
            const int col = t * 16 + (lane & 15);
            const int r0  = (lane >> 4) * 4;
            #pragma unroll
            for (int r = 0; r < 4; ++r)
                Lbs[(r0 + r) * LTS2 + col] = f2bf(c[r]);
        }

        // ---- sigmoid of current gates (resident) ---------------------------
        float g[16];
        #pragma unroll
        for (int i = 0; i < 16; ++i)
            g[i] = 1.0f / (1.0f + __expf(-gn[i]));

        const int gout = gb;       // store base for this step

        __syncthreads();           // single barrier: Lb[s&1] complete

        // ---- prefetch step s+1 AFTER the barrier (drain never waits on it) -
        if (s < 3) {
            rowbase += 16;
            gb += 16 * 256;
            const float* qp2 = query + rowbase * 64 + (lane & 15) * 64 + (lane >> 4) * 8;
            q00 = *(const f32x4*)(qp2);
            q01 = *(const f32x4*)(qp2 + 4);
            q10 = *(const f32x4*)(qp2 + 32);
            q11 = *(const f32x4*)(qp2 + 36);
            const float* gp2 = attn_logits + gb + tid;
            #pragma unroll
            for (int i = 0; i < 16; ++i)
                gn[i] = gp2[i * 256];
        }

        // ---- phase D: pos_h/pos_w -> gather+lerp -> out --------------------
        float* op = out + gout + tid;
        float run = 0.f;
        #pragma unroll
        for (int half = 1; half >= 0; --half) {
            const int i0 = half * 8;
            float r8[8];
            #pragma unroll
            for (int k = 7; k >= 0; --k) { run += g[i0 + k]; r8[k] = run; }

            float w8[8]; int fi8[8];
            #pragma unroll
            for (int k = 0; k < 8; ++k) {
                float pw = suffix_step<8>(suffix_step<4>(suffix_step<2>(suffix_step<1>(g[i0 + k]))));
                float pos = fminf(r8[k] * 16.0f + pw, 287.0f);
                float pf = floorf(pos);
                fi8[k] = (int)pf;
                w8[k]  = pos - pf;
            }
            float lf8[8], lc8[8];
            #pragma unroll
            for (int k = 0; k < 8; ++k) {
                const unsigned short* Lr = Lbs + (i0 + k) * LTS2;
                lf8[k] = bf2f(Lr[fi8[k]]);
                lc8[k] = bf2f(Lr[fi8[k] + 1]);
            }
            #pragma unroll
            for (int k = 0; k < 8; ++k)
                op[(i0 + k) * 256] = lf8[k] + w8[k] * (lc8[k] - lf8[k]);
        }
    }
}

extern "C" void kernel_launch(void* const* d_in, const int* in_sizes, int n_in,
                              void* d_out, int out_size, void* d_ws, size_t ws_size,
                              hipStream_t stream) {
    const float* query       = (const float*)d_in[0];
    const float* attn_logits = (const float*)d_in[1];
    const float* pos_emb     = (const float*)d_in[2];
    float* outp = (float*)d_out;
    short* wsb  = (short*)d_ws;          // NT*2*64*8 bf16 = 36 KB

    prep_kernel<<<9, 256, 0, stream>>>(pos_emb, wsb);
    cope2d_kernel<<<4096, 256, 0, stream>>>(query, attn_logits,
                                            (const bf16x8*)d_ws, outp);
}

// Round 9
// 138.410 us; speedup vs baseline: 1.4716x; 1.4716x over previous
//
#include <hip/hip_runtime.h>

// CoPE2d: B=64, NH=16, Wh=Ww=16, N=256, C=64, NPOS=288, BH=1024
// query (BH,256,64) f32; attn_logits (BH,256,256) f32; pos_emb (64,288) f32;
// out (BH,256,256) f32.
// One block = 4 consecutive 16-row blocks of one bh, software-pipelined with
// double-buffered bf16 L-table -> ONE barrier per step. 256 thr, 6 blocks/CU
// (VGPR cap ~85: R8's (256,8) forced a 64-reg cap -> massive scratch spills).

#define NPOS 288
#define NT   18          // npos tiles of 16
#define LTS2 292         // bf16 Ltab row stride (u16 elements)

typedef __attribute__((ext_vector_type(8))) short bf16x8;
typedef __attribute__((ext_vector_type(4))) float f32x4;

__device__ __forceinline__ unsigned short f2bf(float f) {   // RNE f32->bf16
    unsigned u = __float_as_uint(f);
    u += 0x7FFF + ((u >> 16) & 1);
    return (unsigned short)(u >> 16);
}
__device__ __forceinline__ float bf2f(unsigned short b) {
    return __uint_as_float(((unsigned)b) << 16);
}
// packed f32x2 -> bf16x2 (RNE), single VALU op
__device__ __forceinline__ unsigned cvt_pk_bf16(float lo, float hi) {
    unsigned r;
    asm("v_cvt_pk_bf16_f32 %0, %1, %2" : "=v"(r) : "v"(lo), "v"(hi));
    return r;
}

// dst[i] = src[i] + src[i+D] within 16-lane DPP rows, 0 beyond row end.
template <int D>
__device__ __forceinline__ float suffix_step(float v) {
    int s = __builtin_amdgcn_update_dpp(0, __float_as_int(v), 0x100 | D, 0xF, 0xF, true);
    return v + __int_as_float(s);
}

// ---- prep: pos_emb (64x288 f32) -> bf16 B-fragments in ws ------------------
__global__ void prep_kernel(const float* __restrict__ pos_emb,
                            short* __restrict__ wsb) {
    int idx = blockIdx.x * blockDim.x + threadIdx.x;   // 0 .. NT*2*64
    if (idx >= NT * 2 * 64) return;
    int l = idx & 63;
    int s = (idx >> 6) & 1;
    int t = idx >> 7;
    int col = t * 16 + (l & 15);
    int k0  = s * 32 + (l >> 4) * 8;
    short* dst = wsb + idx * 8;
    #pragma unroll
    for (int j = 0; j < 8; ++j)
        dst[j] = (short)f2bf(pos_emb[(k0 + j) * NPOS + col]);
}

__global__ __launch_bounds__(256, 6) void cope2d_kernel(
    const float* __restrict__ query,
    const float* __restrict__ attn_logits,
    const bf16x8* __restrict__ wsb8,
    float* __restrict__ out)
{
    __shared__ unsigned short Lb[2][16 * LTS2];   // 2 x 9344 B, double-buffered

    const int tid  = threadIdx.x;
    const int lane = tid & 63;
    const int wave = tid >> 6;
    const int blk  = blockIdx.x;               // 0..4095
    const int bh   = blk >> 2;
    const int p0   = (blk & 3) * 4;

    int rowbase = bh * 256 + p0 * 16;          // fits 32-bit
    int gb      = rowbase * 256;               // element idx < 2^26

    // ---- prologue: prefetch q + gates for step 0 ---------------------------
    const float* qp = query + rowbase * 64 + (lane & 15) * 64 + (lane >> 4) * 8;
    f32x4 q00 = *(const f32x4*)(qp);
    f32x4 q01 = *(const f32x4*)(qp + 4);
    f32x4 q10 = *(const f32x4*)(qp + 32);
    f32x4 q11 = *(const f32x4*)(qp + 36);
    float gn[16];
    {
        const float* gp = attn_logits + gb + tid;
        #pragma unroll
        for (int i = 0; i < 16; ++i)
            gn[i] = gp[i * 256];               // coalesced
    }

    for (int s = 0; s < 4; ++s) {
        // ---- A fragments via packed cvt (row=lane&15, k=(lane>>4)*8+j) -----
        union { bf16x8 v; unsigned u[4]; } A0, A1;
        A0.u[0] = cvt_pk_bf16(q00[0], q00[1]);
        A0.u[1] = cvt_pk_bf16(q00[2], q00[3]);
        A0.u[2] = cvt_pk_bf16(q01[0], q01[1]);
        A0.u[3] = cvt_pk_bf16(q01[2], q01[3]);
        A1.u[0] = cvt_pk_bf16(q10[0], q10[1]);
        A1.u[1] = cvt_pk_bf16(q10[2], q10[3]);
        A1.u[2] = cvt_pk_bf16(q11[0], q11[1]);
        A1.u[3] = cvt_pk_bf16(q11[2], q11[3]);

        // ---- MFMA GEMM -> Lb[s&1] (bf16) -----------------------------------
        unsigned short* Lbs = Lb[s & 1];
        for (int t = wave; t < NT; t += 4) {
            f32x4 c = {0.f, 0.f, 0.f, 0.f};
            c = __builtin_amdgcn_mfma_f32_16x16x32_bf16(A0.v, wsb8[(t * 2 + 0) * 64 + lane], c, 0, 0, 0);
            c = __builtin_amdgcn_mfma_f32_16x16x32_bf16(A1.v, wsb8[(t * 2 + 1) * 64 + lane], c, 0, 0, 0);
            const int col = t * 16 + (lane & 15);
            const int r0  = (lane >> 4) * 4;
            #pragma unroll
            for (int r = 0; r < 4; ++r)
                Lbs[(r0 + r) * LTS2 + col] = f2bf(c[r]);
        }

        // ---- sigmoid of current gates (resident) ---------------------------
        float g[16];
        #pragma unroll
        for (int i = 0; i < 16; ++i)
            g[i] = 1.0f / (1.0f + __expf(-gn[i]));

        const int gout = gb;       // store base for this step

        __syncthreads();           // single barrier: Lb[s&1] complete

        // ---- prefetch step s+1 AFTER the barrier (drain never waits on it) -
        if (s < 3) {
            rowbase += 16;
            gb += 16 * 256;
            const float* qp2 = query + rowbase * 64 + (lane & 15) * 64 + (lane >> 4) * 8;
            q00 = *(const f32x4*)(qp2);
            q01 = *(const f32x4*)(qp2 + 4);
            q10 = *(const f32x4*)(qp2 + 32);
            q11 = *(const f32x4*)(qp2 + 36);
            const float* gp2 = attn_logits + gb + tid;
            #pragma unroll
            for (int i = 0; i < 16; ++i)
                gn[i] = gp2[i * 256];
        }

        // ---- phase D: pos_h/pos_w -> gather+lerp -> out --------------------
        float* op = out + gout + tid;
        float run = 0.f;
        #pragma unroll
        for (int half = 1; half >= 0; --half) {
            const int i0 = half * 8;
            float r8[8];
            #pragma unroll
            for (int k = 7; k >= 0; --k) { run += g[i0 + k]; r8[k] = run; }

            float w8[8]; int fi8[8];
            #pragma unroll
            for (int k = 0; k < 8; ++k) {
                float pw = suffix_step<8>(suffix_step<4>(suffix_step<2>(suffix_step<1>(g[i0 + k]))));
                float pos = fminf(r8[k] * 16.0f + pw, 287.0f);
                float pf = floorf(pos);
                fi8[k] = (int)pf;
                w8[k]  = pos - pf;
            }
            float lf8[8], lc8[8];
            #pragma unroll
            for (int k = 0; k < 8; ++k) {
                const unsigned short* Lr = Lbs + (i0 + k) * LTS2;
                lf8[k] = bf2f(Lr[fi8[k]]);
                lc8[k] = bf2f(Lr[fi8[k] + 1]);
            }
            #pragma unroll
            for (int k = 0; k < 8; ++k)
                op[(i0 + k) * 256] = lf8[k] + w8[k] * (lc8[k] - lf8[k]);
        }
    }
}

extern "C" void kernel_launch(void* const* d_in, const int* in_sizes, int n_in,
                              void* d_out, int out_size, void* d_ws, size_t ws_size,
                              hipStream_t stream) {
    const float* query       = (const float*)d_in[0];
    const float* attn_logits = (const float*)d_in[1];
    const float* pos_emb     = (const float*)d_in[2];
    float* outp = (float*)d_out;
    short* wsb  = (short*)d_ws;          // NT*2*64*8 bf16 = 36 KB

    prep_kernel<<<9, 256, 0, stream>>>(pos_emb, wsb);
    cope2d_kernel<<<4096, 256, 0, stream>>>(query, attn_logits,
                                            (const bf16x8*)d_ws, outp);
}

// Round 10
// 122.832 us; speedup vs baseline: 1.6582x; 1.1268x over previous
//
#include <hip/hip_runtime.h>

// CoPE2d: B=64, NH=16, Wh=Ww=16, N=256, C=64, NPOS=288, BH=1024
// query (BH,256,64) f32; attn_logits (BH,256,256) f32; pos_emb (64,288) f32;
// out (BH,256,256) f32.
// One block = 4 consecutive 16-row blocks of one bh, software-pipelined,
// double-buffered f32 L-table (37.4 KB LDS), ONE barrier per step.
// 256 thr, 4 blocks/CU (16 waves/CU), VGPR cap 128 (no spills).

#define NPOS 288
#define NT   18          // npos tiles of 16
#define LTSF 292         // f32 Ltab row stride (padded)

typedef __attribute__((ext_vector_type(8))) short bf16x8;
typedef __attribute__((ext_vector_type(4))) float f32x4;

__device__ __forceinline__ unsigned short f2bf(float f) {   // RNE f32->bf16
    unsigned u = __float_as_uint(f);
    u += 0x7FFF + ((u >> 16) & 1);
    return (unsigned short)(u >> 16);
}
// packed f32x2 -> bf16x2 (RNE), single VALU op
__device__ __forceinline__ unsigned cvt_pk_bf16(float lo, float hi) {
    unsigned r;
    asm("v_cvt_pk_bf16_f32 %0, %1, %2" : "=v"(r) : "v"(lo), "v"(hi));
    return r;
}

// dst[i] = src[i] + src[i+D] within 16-lane DPP rows, 0 beyond row end.
template <int D>
__device__ __forceinline__ float suffix_step(float v) {
    int s = __builtin_amdgcn_update_dpp(0, __float_as_int(v), 0x100 | D, 0xF, 0xF, true);
    return v + __int_as_float(s);
}

// ---- prep: pos_emb (64x288 f32) -> bf16 B-fragments in ws ------------------
__global__ void prep_kernel(const float* __restrict__ pos_emb,
                            short* __restrict__ wsb) {
    int idx = blockIdx.x * blockDim.x + threadIdx.x;   // 0 .. NT*2*64
    if (idx >= NT * 2 * 64) return;
    int l = idx & 63;
    int s = (idx >> 6) & 1;
    int t = idx >> 7;
    int col = t * 16 + (l & 15);
    int k0  = s * 32 + (l >> 4) * 8;
    short* dst = wsb + idx * 8;
    #pragma unroll
    for (int j = 0; j < 8; ++j)
        dst[j] = (short)f2bf(pos_emb[(k0 + j) * NPOS + col]);
}

__global__ __launch_bounds__(256, 4) void cope2d_kernel(
    const float* __restrict__ query,
    const float* __restrict__ attn_logits,
    const bf16x8* __restrict__ wsb8,
    float* __restrict__ out)
{
    __shared__ float Lf[2][16 * LTSF];   // 2 x 18688 B, double-buffered

    const int tid  = threadIdx.x;
    const int lane = tid & 63;
    const int wave = tid >> 6;
    const int blk  = blockIdx.x;               // 0..4095
    const int bh   = blk >> 2;
    const int p0   = (blk & 3) * 4;

    int rowbase = bh * 256 + p0 * 16;          // fits 32-bit
    int gb      = rowbase * 256;               // element idx < 2^26

    // ---- B fragments: load ONCE per block, reused all 4 steps --------------
    bf16x8 Bf[5][2];
    #pragma unroll
    for (int u = 0; u < 5; ++u) {
        int t = wave + 4 * u;
        if (t < NT) {
            Bf[u][0] = wsb8[(t * 2 + 0) * 64 + lane];
            Bf[u][1] = wsb8[(t * 2 + 1) * 64 + lane];
        }
    }

    // ---- prologue: prefetch q + gates for step 0 ---------------------------
    const float* qp = query + rowbase * 64 + (lane & 15) * 64 + (lane >> 4) * 8;
    f32x4 q00 = *(const f32x4*)(qp);
    f32x4 q01 = *(const f32x4*)(qp + 4);
    f32x4 q10 = *(const f32x4*)(qp + 32);
    f32x4 q11 = *(const f32x4*)(qp + 36);
    float gn[16];
    {
        const float* gp = attn_logits + gb + tid;
        #pragma unroll
        for (int i = 0; i < 16; ++i)
            gn[i] = gp[i * 256];               // coalesced
    }

    for (int s = 0; s < 4; ++s) {
        // ---- A fragments via packed cvt (row=lane&15, k=(lane>>4)*8+j) -----
        union { bf16x8 v; unsigned u[4]; } A0, A1;
        A0.u[0] = cvt_pk_bf16(q00[0], q00[1]);
        A0.u[1] = cvt_pk_bf16(q00[2], q00[3]);
        A0.u[2] = cvt_pk_bf16(q01[0], q01[1]);
        A0.u[3] = cvt_pk_bf16(q01[2], q01[3]);
        A1.u[0] = cvt_pk_bf16(q10[0], q10[1]);
        A1.u[1] = cvt_pk_bf16(q10[2], q10[3]);
        A1.u[2] = cvt_pk_bf16(q11[0], q11[1]);
        A1.u[3] = cvt_pk_bf16(q11[2], q11[3]);

        // ---- MFMA GEMM -> Lf[s&1] (f32, no conversion) ---------------------
        float* Lfs = Lf[s & 1];
        #pragma unroll
        for (int u = 0; u < 5; ++u) {
            int t = wave + 4 * u;
            if (t < NT) {
                f32x4 c = {0.f, 0.f, 0.f, 0.f};
                c = __builtin_amdgcn_mfma_f32_16x16x32_bf16(A0.v, Bf[u][0], c, 0, 0, 0);
                c = __builtin_amdgcn_mfma_f32_16x16x32_bf16(A1.v, Bf[u][1], c, 0, 0, 0);
                const int col = t * 16 + (lane & 15);
                const int r0  = (lane >> 4) * 4;
                #pragma unroll
                for (int r = 0; r < 4; ++r)
                    Lfs[(r0 + r) * LTSF + col] = c[r];
            }
        }

        // ---- sigmoid of current gates (resident) ---------------------------
        float g[16];
        #pragma unroll
        for (int i = 0; i < 16; ++i)
            g[i] = 1.0f / (1.0f + __expf(-gn[i]));

        const int gout = gb;       // store base for this step

        __syncthreads();           // single barrier: Lf[s&1] complete

        // ---- prefetch step s+1 AFTER the barrier ---------------------------
        if (s < 3) {
            rowbase += 16;
            gb += 16 * 256;
            const float* qp2 = query + rowbase * 64 + (lane & 15) * 64 + (lane >> 4) * 8;
            q00 = *(const f32x4*)(qp2);
            q01 = *(const f32x4*)(qp2 + 4);
            q10 = *(const f32x4*)(qp2 + 32);
            q11 = *(const f32x4*)(qp2 + 36);
            const float* gp2 = attn_logits + gb + tid;
            #pragma unroll
            for (int i = 0; i < 16; ++i)
                gn[i] = gp2[i * 256];
        }

        // ---- phase D: pos_h/pos_w -> gather+lerp -> out --------------------
        // pos = sfx*16 + pw <= 16*16 + 16 = 272 < 287: clamp is identity.
        float* op = out + gout + tid;
        float run = 0.f;
        #pragma unroll
        for (int half = 1; half >= 0; --half) {
            const int i0 = half * 8;
            float r8[8];
            #pragma unroll
            for (int k = 7; k >= 0; --k) { run += g[i0 + k]; r8[k] = run; }

            float w8[8]; int fi8[8];
            #pragma unroll
            for (int k = 0; k < 8; ++k) {
                float pw = suffix_step<8>(suffix_step<4>(suffix_step<2>(suffix_step<1>(g[i0 + k]))));
                float pos = r8[k] * 16.0f + pw;
                float pf = floorf(pos);
                fi8[k] = (int)pf;
                w8[k]  = pos - pf;
            }
            float lf8[8], lc8[8];
            #pragma unroll
            for (int k = 0; k < 8; ++k) {
                const float* Lr = Lfs + (i0 + k) * LTSF;
                lf8[k] = Lr[fi8[k]];
                lc8[k] = Lr[fi8[k] + 1];    // same addr + offset:4
            }
            #pragma unroll
            for (int k = 0; k < 8; ++k)
                op[(i0 + k) * 256] = lf8[k] + w8[k] * (lc8[k] - lf8[k]);
        }
    }
}

extern "C" void kernel_launch(void* const* d_in, const int* in_sizes, int n_in,
                              void* d_out, int out_size, void* d_ws, size_t ws_size,
                              hipStream_t stream) {
    const float* query       = (const float*)d_in[0];
    const float* attn_logits = (const float*)d_in[1];
    const float* pos_emb     = (const float*)d_in[2];
    float* outp = (float*)d_out;
    short* wsb  = (short*)d_ws;          // NT*2*64*8 bf16 = 36 KB

    prep_kernel<<<9, 256, 0, stream>>>(pos_emb, wsb);
    cope2d_kernel<<<4096, 256, 0, stream>>>(query, attn_logits,
                                            (const bf16x8*)d_ws, outp);
}

// Round 11
// 121.966 us; speedup vs baseline: 1.6700x; 1.0071x over previous
//
#include <hip/hip_runtime.h>

// CoPE2d: B=64, NH=16, Wh=Ww=16, N=256, C=64, NPOS=288, BH=1024
// query (BH,256,64) f32; attn_logits (BH,256,256) f32; pos_emb (64,288) f32;
// out (BH,256,256) f32.
// One block = 4 consecutive 16-row blocks of one bh, software-pipelined,
// double-buffered f32 L-table, ONE RAW barrier per step (lgkmcnt-only wait —
// stores & prefetch loads never drained at barriers). 256 thr, 4 blocks/CU.

#define NPOS 288
#define NT   18          // npos tiles of 16
#define LTSF 292         // f32 Ltab row stride (padded)

typedef __attribute__((ext_vector_type(8))) short bf16x8;
typedef __attribute__((ext_vector_type(4))) float f32x4;

__device__ __forceinline__ unsigned short f2bf(float f) {   // RNE f32->bf16
    unsigned u = __float_as_uint(f);
    u += 0x7FFF + ((u >> 16) & 1);
    return (unsigned short)(u >> 16);
}
// packed f32x2 -> bf16x2 (RNE), single VALU op
__device__ __forceinline__ unsigned cvt_pk_bf16(float lo, float hi) {
    unsigned r;
    asm("v_cvt_pk_bf16_f32 %0, %1, %2" : "=v"(r) : "v"(lo), "v"(hi));
    return r;
}
__device__ __forceinline__ float fast_exp2(float x) {   // v_exp_f32 = 2^x
    float r;
    asm("v_exp_f32 %0, %1" : "=v"(r) : "v"(x));
    return r;
}
__device__ __forceinline__ float fast_fract(float x) {  // x - floor(x)
    float r;
    asm("v_fract_f32 %0, %1" : "=v"(r) : "v"(x));
    return r;
}

// dst[i] = src[i] + src[i+D] within 16-lane DPP rows, 0 beyond row end.
template <int D>
__device__ __forceinline__ float suffix_step(float v) {
    int s = __builtin_amdgcn_update_dpp(0, __float_as_int(v), 0x100 | D, 0xF, 0xF, true);
    return v + __int_as_float(s);
}

// ---- prep: pos_emb (64x288 f32) -> bf16 B-fragments in ws ------------------
__global__ void prep_kernel(const float* __restrict__ pos_emb,
                            short* __restrict__ wsb) {
    int idx = blockIdx.x * blockDim.x + threadIdx.x;   // 0 .. NT*2*64
    if (idx >= NT * 2 * 64) return;
    int l = idx & 63;
    int s = (idx >> 6) & 1;
    int t = idx >> 7;
    int col = t * 16 + (l & 15);
    int k0  = s * 32 + (l >> 4) * 8;
    short* dst = wsb + idx * 8;
    #pragma unroll
    for (int j = 0; j < 8; ++j)
        dst[j] = (short)f2bf(pos_emb[(k0 + j) * NPOS + col]);
}

__global__ __launch_bounds__(256, 4) void cope2d_kernel(
    const float* __restrict__ query,
    const float* __restrict__ attn_logits,
    const bf16x8* __restrict__ wsb8,
    float* __restrict__ out)
{
    __shared__ float Lf[2][16 * LTSF];   // 2 x 18688 B, double-buffered

    const int tid  = threadIdx.x;
    const int lane = tid & 63;
    const int wave = tid >> 6;
    const int blk  = blockIdx.x;               // 0..4095
    const int bh   = blk >> 2;
    const int p0   = (blk & 3) * 4;

    int rowbase = bh * 256 + p0 * 16;          // fits 32-bit
    int gb      = rowbase * 256;               // element idx < 2^26

    // ---- B fragments: load ONCE per block, reused all 4 steps --------------
    // (also keeps all per-step VMEM loads issued BEFORE the step's stores,
    //  so no consumer's vmcnt wait ever forces a store drain)
    bf16x8 Bf[5][2];
    #pragma unroll
    for (int u = 0; u < 5; ++u) {
        int t = wave + 4 * u;
        if (t < NT) {
            Bf[u][0] = wsb8[(t * 2 + 0) * 64 + lane];
            Bf[u][1] = wsb8[(t * 2 + 1) * 64 + lane];
        }
    }

    // ---- prologue: prefetch q + gates for step 0 ---------------------------
    const float* qp = query + rowbase * 64 + (lane & 15) * 64 + (lane >> 4) * 8;
    f32x4 q00 = *(const f32x4*)(qp);
    f32x4 q01 = *(const f32x4*)(qp + 4);
    f32x4 q10 = *(const f32x4*)(qp + 32);
    f32x4 q11 = *(const f32x4*)(qp + 36);
    float gn[16];
    {
        const float* gp = attn_logits + gb + tid;
        #pragma unroll
        for (int i = 0; i < 16; ++i)
            gn[i] = gp[i * 256];               // coalesced
    }

    for (int s = 0; s < 4; ++s) {
        // ---- A fragments via packed cvt (row=lane&15, k=(lane>>4)*8+j) -----
        union { bf16x8 v; unsigned u[4]; } A0, A1;
        A0.u[0] = cvt_pk_bf16(q00[0], q00[1]);
        A0.u[1] = cvt_pk_bf16(q00[2], q00[3]);
        A0.u[2] = cvt_pk_bf16(q01[0], q01[1]);
        A0.u[3] = cvt_pk_bf16(q01[2], q01[3]);
        A1.u[0] = cvt_pk_bf16(q10[0], q10[1]);
        A1.u[1] = cvt_pk_bf16(q10[2], q10[3]);
        A1.u[2] = cvt_pk_bf16(q11[0], q11[1]);
        A1.u[3] = cvt_pk_bf16(q11[2], q11[3]);

        // ---- MFMA GEMM -> Lf[s&1] (f32) ------------------------------------
        float* Lfs = Lf[s & 1];
        #pragma unroll
        for (int u = 0; u < 5; ++u) {
            int t = wave + 4 * u;
            if (t < NT) {
                f32x4 c = {0.f, 0.f, 0.f, 0.f};
                c = __builtin_amdgcn_mfma_f32_16x16x32_bf16(A0.v, Bf[u][0], c, 0, 0, 0);
                c = __builtin_amdgcn_mfma_f32_16x16x32_bf16(A1.v, Bf[u][1], c, 0, 0, 0);
                const int col = t * 16 + (lane & 15);
                const int r0  = (lane >> 4) * 4;
                #pragma unroll
                for (int r = 0; r < 4; ++r)
                    Lfs[(r0 + r) * LTSF + col] = c[r];
            }
        }

        // ---- sigmoid of current gates: 1/(1 + 2^(-x*log2e)) ----------------
        float g[16];
        #pragma unroll
        for (int i = 0; i < 16; ++i) {
            float e = fast_exp2(gn[i] * -1.44269504088896f);
            g[i] = __builtin_amdgcn_rcpf(1.0f + e);
        }

        const int gout = gb;       // store base for this step

        // ---- RAW barrier: drain LDS writes only; stores/prefetch untouched -
        asm volatile("s_waitcnt lgkmcnt(0)" ::: "memory");
        __builtin_amdgcn_s_barrier();

        // ---- prefetch step s+1 (in flight under phase D + next GEMM) -------
        if (s < 3) {
            rowbase += 16;
            gb += 16 * 256;
            const float* qp2 = query + rowbase * 64 + (lane & 15) * 64 + (lane >> 4) * 8;
            q00 = *(const f32x4*)(qp2);
            q01 = *(const f32x4*)(qp2 + 4);
            q10 = *(const f32x4*)(qp2 + 32);
            q11 = *(const f32x4*)(qp2 + 36);
            const float* gp2 = attn_logits + gb + tid;
            #pragma unroll
            for (int i = 0; i < 16; ++i)
                gn[i] = gp2[i * 256];
        }

        // ---- phase D: pos_h/pos_w -> gather+lerp -> out --------------------
        // pos = sfx*16 + pw <= 272 < 287: clamp is identity; fi+1 <= 273 < 292.
        float* op = out + gout + tid;
        float run = 0.f;
        #pragma unroll
        for (int half = 1; half >= 0; --half) {
            const int i0 = half * 8;
            float r8[8];
            #pragma unroll
            for (int k = 7; k >= 0; --k) { run += g[i0 + k]; r8[k] = run; }

            float w8[8]; int fi8[8];
            #pragma unroll
            for (int k = 0; k < 8; ++k) {
                float pw = suffix_step<8>(suffix_step<4>(suffix_step<2>(suffix_step<1>(g[i0 + k]))));
                float pos = r8[k] * 16.0f + pw;
                fi8[k] = (int)pos;              // trunc == floor (pos >= 0)
                w8[k]  = fast_fract(pos);       // pos - floor(pos)
            }
            float lf8[8], lc8[8];
            #pragma unroll
            for (int k = 0; k < 8; ++k) {
                const float* Lr = Lfs + (i0 + k) * LTSF;
                lf8[k] = Lr[fi8[k]];
                lc8[k] = Lr[fi8[k] + 1];
            }
            #pragma unroll
            for (int k = 0; k < 8; ++k)
                op[(i0 + k) * 256] = lf8[k] + w8[k] * (lc8[k] - lf8[k]);
        }
        // NO end-of-step barrier needed: phase-D read values are consumed
        // before this point; cross-wave WAR on Lf[s&1] is covered by the two
        // intervening raw barriers of steps s+1 and s+2 (double buffer).
    }
}

extern "C" void kernel_launch(void* const* d_in, const int* in_sizes, int n_in,
                              void* d_out, int out_size, void* d_ws, size_t ws_size,
                              hipStream_t stream) {
    const float* query       = (const float*)d_in[0];
    const float* attn_logits = (const float*)d_in[1];
    const float* pos_emb     = (const float*)d_in[2];
    float* outp = (float*)d_out;
    short* wsb  = (short*)d_ws;          // NT*2*64*8 bf16 = 36 KB

    prep_kernel<<<9, 256, 0, stream>>>(pos_emb, wsb);
    cope2d_kernel<<<4096, 256, 0, stream>>>(query, attn_logits,
                                            (const bf16x8*)d_ws, outp);
}